// Round 3
// baseline (636.254 us; speedup 1.0000x reference)
//
#include <hip/hip_runtime.h>
#include <math.h>

typedef __attribute__((ext_vector_type(8))) short bf8v;
typedef __attribute__((ext_vector_type(4))) float f4v;

#define B_      8
#define CIN_    256
#define C_      128
#define NPIX_   16384
#define EPS_    1e-12f
#define BN_EPS_ 1e-5f
#define TPB2_   2

// workspace byte offsets (all 256-aligned)
#define OFF_WK1  0u          // 128x256 bf16 = 65536 B
#define OFF_WV   65536u
#define OFF_WQ1  131072u
#define OFF_WK2  196608u     // 128x128 bf16 = 32768 B
#define OFF_WQ2  229376u
#define OFF_BIAS 262144u     // 5*128 f32 [bk1,bv,bq1,bk2,bq2]
#define OFF_S    264704u     // 8*128*128 f32 = 524288 B
#define OFF_Z    788992u     // 8*128 f32 = 4096 B
#define OFF_SBF  793088u     // 8*128*128 bf16 = 262144 B
#define OFF_VAL  1055232u    // 8*128*16384 bf16 = 33554432 B
#define OFF_KEY  34609664u   // 8*128*16384 bf16 = 33554432 B

__device__ __forceinline__ unsigned short f2bf(float f) {
    unsigned u = __float_as_uint(f);
    unsigned r = u + 0x7fffu + ((u >> 16) & 1u);
    return (unsigned short)(r >> 16);
}
__device__ __forceinline__ float lo16(unsigned v){ return __uint_as_float(v << 16); }
__device__ __forceinline__ float hi16(unsigned v){ return __uint_as_float(v & 0xffff0000u); }
__device__ __forceinline__ float softplus_f(float x) {
    return fmaxf(x, 0.f) + __logf(1.f + __expf(-fabsf(x)));
}
__device__ __forceinline__ f4v MFMA(bf8v a, bf8v b, f4v c) {
    return __builtin_amdgcn_mfma_f32_16x16x32_bf16(a, b, c, 0, 0, 0);
}

struct PrepPtrs {
    const float* w[5];
    const float* g[5];
    const float* be[5];
    const float* mu[5];
    const float* va[5];
    unsigned short* wout[5];
    float* bout[5];
};

// Fold BN into weights (bf16) + bias (f32). order: 0=k1,1=v,2=q1 (cin=256), 3=k2,4=q2 (cin=128)
__global__ void prep_kernel(PrepPtrs p) {
    int idx = blockIdx.x * 256 + threadIdx.x;
    if (idx < 131072) {
        int conv, local, sh;
        if (idx < 32768)       { conv = 0; local = idx;          sh = 8; }
        else if (idx < 65536)  { conv = 1; local = idx - 32768;  sh = 8; }
        else if (idx < 98304)  { conv = 2; local = idx - 65536;  sh = 8; }
        else if (idx < 114688) { conv = 3; local = idx - 98304;  sh = 7; }
        else                   { conv = 4; local = idx - 114688; sh = 7; }
        int o = local >> sh;
        float scale = p.g[conv][o] * rsqrtf(p.va[conv][o] + BN_EPS_);
        p.wout[conv][local] = f2bf(p.w[conv][local] * scale);
    } else if (idx < 131712) {
        int j = idx - 131072;
        int conv = j >> 7;
        int o = j & 127;
        float scale = p.g[conv][o] * rsqrtf(p.va[conv][o] + BN_EPS_);
        p.bout[conv][o] = p.be[conv][o] - p.mu[conv][o] * scale;
    }
}

// xT swizzle: row n (64 rows, 256 ushorts each); 16B chunk c at column ((c ^ (n&31))<<3)
// makes both transpose-writes and b128 reads <=2-way bank conflicts (free).

// ---------------- source branch: value & key to HBM (bf16, [b][c][n]) ----------------
__global__ __launch_bounds__(512, 4)
void srcKV(const float* __restrict__ src,
           const unsigned short* __restrict__ Wk1, const unsigned short* __restrict__ Wv,
           const unsigned short* __restrict__ Wk2, const float* __restrict__ bias,
           unsigned short* __restrict__ valg, unsigned short* __restrict__ keyg)
{
    __shared__ __align__(16) char smem[50176];
    unsigned short* xT   = (unsigned short*)smem;            // swizzled [64][256] = 32768 B
    unsigned short* hT   = (unsigned short*)(smem + 32768);  // [64][136] = 17408 B
    unsigned short* stgV = (unsigned short*)smem;            // [128][72] aliases xT (post-sync)
    unsigned short* stgK = (unsigned short*)(smem + 18432);  // [128][72]

    const int tid = threadIdx.x;
    const int L = tid & 63, w = tid >> 6;
    const int lr = L & 15, qd = L >> 4;
    const int b = blockIdx.y;
    const int m0 = w * 16;
    const int kbq = qd * 8;
    const float* bk1 = bias;
    const float* bvp = bias + 128;
    const float* bk2 = bias + 384;
    const int pn4 = (tid & 15) * 4;

    float4 pf[8];
    int tile = blockIdx.x * TPB2_;
    {   // prologue prefetch of tile 0
        const int gn0 = tile * 64;
        #pragma unroll
        for (int s = 0; s < 2; s++) {
            const int k0 = ((tid >> 4) + s * 32) * 4;
            const float* gp = src + (size_t)(b * 256 + k0) * NPIX_ + gn0 + pn4;
            #pragma unroll
            for (int i = 0; i < 4; i++)
                pf[s * 4 + i] = *(const float4*)(gp + (size_t)i * NPIX_);
        }
    }

    for (int tt = 0; tt < TPB2_; tt++, tile++) {
        const int gn0 = tile * 64;
        if (tt) __syncthreads();   // prior copy-out reads of stg region complete
        // stage x (transpose fp32->bf16, swizzled)
        #pragma unroll
        for (int s = 0; s < 2; s++) {
            const int k0 = ((tid >> 4) + s * 32) * 4;
            const int c = k0 >> 3, h4 = k0 & 4;
            #pragma unroll
            for (int j = 0; j < 4; j++) {
                const int row = pn4 + j;
                ushort4 t;
                t.x = f2bf(((const float*)&pf[s*4+0])[j]);
                t.y = f2bf(((const float*)&pf[s*4+1])[j]);
                t.z = f2bf(((const float*)&pf[s*4+2])[j]);
                t.w = f2bf(((const float*)&pf[s*4+3])[j]);
                *(ushort4*)(xT + row * 256 + (((c ^ (row & 31)) << 3) | h4)) = t;
            }
        }
        __syncthreads();
        if (tt + 1 < TPB2_) {   // prefetch next tile during compute
            const int gn1 = (tile + 1) * 64;
            #pragma unroll
            for (int s = 0; s < 2; s++) {
                const int k0 = ((tid >> 4) + s * 32) * 4;
                const float* gp = src + (size_t)(b * 256 + k0) * NPIX_ + gn1 + pn4;
                #pragma unroll
                for (int i = 0; i < 4; i++)
                    pf[s * 4 + i] = *(const float4*)(gp + (size_t)i * NPIX_);
            }
        }

        // P1: h = Wk1*x, val = Wv*x (per wave: 16 rows x 64 pixels)
        f4v zz = {0.f, 0.f, 0.f, 0.f};
        f4v hA[4] = {zz, zz, zz, zz}, vA[4] = {zz, zz, zz, zz};
        #pragma unroll
        for (int ks = 0; ks < 8; ks++) {
            const int kb = ks * 32 + kbq;
            const int cch = kb >> 3;
            bf8v a1 = *(const bf8v*)(Wk1 + (m0 + lr) * 256 + kb);
            bf8v a2 = *(const bf8v*)(Wv  + (m0 + lr) * 256 + kb);
            bf8v bx[4];
            #pragma unroll
            for (int nt = 0; nt < 4; nt++) {
                const int row = nt * 16 + lr;
                bx[nt] = *(const bf8v*)(xT + row * 256 + ((cch ^ (row & 31)) << 3));
            }
            #pragma unroll
            for (int nt = 0; nt < 4; nt++) {
                hA[nt] = MFMA(a1, bx[nt], hA[nt]);
                vA[nt] = MFMA(a2, bx[nt], vA[nt]);
            }
        }
        // epilogue: h -> hT (bias+relu), val bias+relu in regs
        {
            const float4 b4 = *(const float4*)(bk1 + m0 + qd * 4);
            #pragma unroll
            for (int nt = 0; nt < 4; nt++) {
                ushort4 t;
                t.x = f2bf(fmaxf(hA[nt][0] + b4.x, 0.f));
                t.y = f2bf(fmaxf(hA[nt][1] + b4.y, 0.f));
                t.z = f2bf(fmaxf(hA[nt][2] + b4.z, 0.f));
                t.w = f2bf(fmaxf(hA[nt][3] + b4.w, 0.f));
                *(ushort4*)(hT + (nt * 16 + lr) * 136 + m0 + qd * 4) = t;
            }
            const float4 bv4 = *(const float4*)(bvp + m0 + qd * 4);
            const float* bp = (const float*)&bv4;
            #pragma unroll
            for (int nt = 0; nt < 4; nt++)
                #pragma unroll
                for (int r = 0; r < 4; r++)
                    vA[nt][r] = fmaxf(vA[nt][r] + bp[r], 0.f);
        }
        __syncthreads();

        // P2: key = Wk2 * h
        f4v kA[4] = {zz, zz, zz, zz};
        #pragma unroll
        for (int ks = 0; ks < 4; ks++) {
            const int kb = ks * 32 + kbq;
            bf8v a = *(const bf8v*)(Wk2 + (m0 + lr) * 128 + kb);
            bf8v bh[4];
            #pragma unroll
            for (int nt = 0; nt < 4; nt++)
                bh[nt] = *(const bf8v*)(hT + (nt * 16 + lr) * 136 + kb);
            #pragma unroll
            for (int nt = 0; nt < 4; nt++)
                kA[nt] = MFMA(a, bh[nt], kA[nt]);
        }
        __syncthreads();   // hT reads done; stg regions free

        // stage val/key into [c][72] layout
        {
            const float4 bK4 = *(const float4*)(bk2 + m0 + qd * 4);
            const float* bp = (const float*)&bK4;
            #pragma unroll
            for (int nt = 0; nt < 4; nt++) {
                const int n = nt * 16 + lr;
                #pragma unroll
                for (int r = 0; r < 4; r++) {
                    const int m = m0 + qd * 4 + r;
                    stgV[m * 72 + n] = f2bf(vA[nt][r]);
                    stgK[m * 72 + n] = f2bf(softplus_f(kA[nt][r] + bp[r]));
                }
            }
        }
        __syncthreads();
        // coalesced copy-out (2 arrays x 128 c x 8 x 16B)
        #pragma unroll
        for (int s = 0; s < 4; s++) {
            const int id2 = tid + s * 512;
            const int arr = id2 >> 10, rem = id2 & 1023;
            const int c = rem >> 3, o = rem & 7;
            uint4 d = *(const uint4*)((arr ? stgK : stgV) + c * 72 + o * 8);
            *(uint4*)((arr ? keyg : valg) + (size_t)(b * 128 + c) * NPIX_ + gn0 + o * 8) = d;
        }
    }
}

// ---------------- S = val . key^T (split-K over pixels), Z = rowsum(key) ----------------
__global__ __launch_bounds__(256, 3)
void skern(const unsigned short* __restrict__ valg, const unsigned short* __restrict__ keyg,
           float* __restrict__ Sbuf, float* __restrict__ Zbuf)
{
    __shared__ __align__(16) unsigned short vs[128 * 72];
    __shared__ __align__(16) unsigned short ks_[128 * 72];
    const int tid = threadIdx.x;
    const int L = tid & 63, w = tid >> 6;
    const int lr = L & 15, qd = L >> 4;
    const int b = blockIdx.x >> 6, ch = blockIdx.x & 63;
    const size_t nbase = (size_t)ch * 256;
    const int m0 = (w & 1) * 64, n0 = (w >> 1) * 64;
    const int sarr = tid >> 7 ? 1 : 0;  // unused marker

    // per-thread staging map
    const int sc[8] = {0,0,0,0,0,0,0,0}; (void)sc; (void)sarr;

    f4v zz = {0.f, 0.f, 0.f, 0.f};
    f4v acc[4][4];
    #pragma unroll
    for (int mt = 0; mt < 4; mt++)
        #pragma unroll
        for (int nt = 0; nt < 4; nt++) acc[mt][nt] = zz;
    float zacc = 0.f;
    const int zc = tid >> 1, zh = tid & 1;

    uint4 pf[8];
    {   // prefetch window 0
        #pragma unroll
        for (int s = 0; s < 8; s++) {
            const int id = tid + s * 256;
            const int arr = id >> 10, rem = id & 1023;
            const int c = rem >> 3, o = rem & 7;
            pf[s] = *(const uint4*)((arr ? keyg : valg) + (size_t)(b * 128 + c) * NPIX_ + nbase + o * 8);
        }
    }

    for (int wd = 0; wd < 4; wd++) {
        #pragma unroll
        for (int s = 0; s < 8; s++) {
            const int id = tid + s * 256;
            const int arr = id >> 10, rem = id & 1023;
            const int c = rem >> 3, o = rem & 7;
            *(uint4*)((arr ? ks_ : vs) + c * 72 + o * 8) = pf[s];
        }
        __syncthreads();
        if (wd < 3) {
            const size_t nw = nbase + (wd + 1) * 64;
            #pragma unroll
            for (int s = 0; s < 8; s++) {
                const int id = tid + s * 256;
                const int arr = id >> 10, rem = id & 1023;
                const int c = rem >> 3, o = rem & 7;
                pf[s] = *(const uint4*)((arr ? keyg : valg) + (size_t)(b * 128 + c) * NPIX_ + nw + o * 8);
            }
        }
        #pragma unroll
        for (int kk = 0; kk < 2; kk++) {
            const int kb = kk * 32 + qd * 8;
            bf8v a[4], bb[4];
            #pragma unroll
            for (int mt = 0; mt < 4; mt++)
                a[mt] = *(const bf8v*)(vs + (m0 + mt * 16 + lr) * 72 + kb);
            #pragma unroll
            for (int nt = 0; nt < 4; nt++)
                bb[nt] = *(const bf8v*)(ks_ + (n0 + nt * 16 + lr) * 72 + kb);
            #pragma unroll
            for (int mt = 0; mt < 4; mt++)
                #pragma unroll
                for (int nt = 0; nt < 4; nt++)
                    acc[mt][nt] = MFMA(a[mt], bb[nt], acc[mt][nt]);
        }
        // Z partial
        {
            const unsigned short* kr = ks_ + zc * 72 + zh * 32;
            #pragma unroll
            for (int p = 0; p < 4; p++) {
                uint4 t = *(const uint4*)(kr + p * 8);
                zacc += lo16(t.x) + hi16(t.x) + lo16(t.y) + hi16(t.y)
                      + lo16(t.z) + hi16(t.z) + lo16(t.w) + hi16(t.w);
            }
        }
        __syncthreads();
    }
    #pragma unroll
    for (int mt = 0; mt < 4; mt++)
        #pragma unroll
        for (int nt = 0; nt < 4; nt++)
            #pragma unroll
            for (int r = 0; r < 4; r++) {
                int m = m0 + mt * 16 + qd * 4 + r;
                int cN = n0 + nt * 16 + lr;
                atomicAdd(Sbuf + ((size_t)b * 128 + m) * 128 + cN, acc[mt][nt][r]);
            }
    atomicAdd(Zbuf + b * 128 + zc, zacc);
}

__global__ void cvts(const float* __restrict__ Sbuf, unsigned short* __restrict__ Sbf) {
    int i = blockIdx.x * 256 + threadIdx.x;
    if (i < 131072) Sbf[i] = f2bf(Sbuf[i]);
}

// ---------------- target branch fused: q1 -> q2 -> S.q / max(Z.q,eps) ----------------
__global__ __launch_bounds__(512, 4)
void tgtAttn(const float* __restrict__ tgt,
             const unsigned short* __restrict__ Wq1, const unsigned short* __restrict__ Wq2,
             const float* __restrict__ bias, const unsigned short* __restrict__ Sbf,
             const float* __restrict__ Zbuf, float* __restrict__ out)
{
    __shared__ __align__(16) char smem[50944];
    unsigned short* xT = (unsigned short*)smem;            // swizzled [64][256]
    unsigned short* hT = (unsigned short*)(smem + 32768);  // [64][136]: q_h then query
    float* dn  = (float*)(smem + 50176);                   // [64]
    float* Zsh = (float*)(smem + 50432);                   // [128]

    const int tid = threadIdx.x;
    const int L = tid & 63, w = tid >> 6;
    const int lr = L & 15, qd = L >> 4;
    const int b = blockIdx.y;
    const int m0 = w * 16;
    const int kbq = qd * 8;
    const float* bq1 = bias + 256;
    const float* bq2 = bias + 512;
    const int pn4 = (tid & 15) * 4;

    if (tid < 128) Zsh[tid] = Zbuf[b * 128 + tid];

    float4 pf[8];
    int tile = blockIdx.x * TPB2_;
    {
        const int gn0 = tile * 64;
        #pragma unroll
        for (int s = 0; s < 2; s++) {
            const int k0 = ((tid >> 4) + s * 32) * 4;
            const float* gp = tgt + (size_t)(b * 256 + k0) * NPIX_ + gn0 + pn4;
            #pragma unroll
            for (int i = 0; i < 4; i++)
                pf[s * 4 + i] = *(const float4*)(gp + (size_t)i * NPIX_);
        }
    }

    for (int tt = 0; tt < TPB2_; tt++, tile++) {
        const int gn0 = tile * 64;
        if (tt) __syncthreads();
        #pragma unroll
        for (int s = 0; s < 2; s++) {
            const int k0 = ((tid >> 4) + s * 32) * 4;
            const int c = k0 >> 3, h4 = k0 & 4;
            #pragma unroll
            for (int j = 0; j < 4; j++) {
                const int row = pn4 + j;
                ushort4 t;
                t.x = f2bf(((const float*)&pf[s*4+0])[j]);
                t.y = f2bf(((const float*)&pf[s*4+1])[j]);
                t.z = f2bf(((const float*)&pf[s*4+2])[j]);
                t.w = f2bf(((const float*)&pf[s*4+3])[j]);
                *(ushort4*)(xT + row * 256 + (((c ^ (row & 31)) << 3) | h4)) = t;
            }
        }
        __syncthreads();
        if (tt + 1 < TPB2_) {
            const int gn1 = (tile + 1) * 64;
            #pragma unroll
            for (int s = 0; s < 2; s++) {
                const int k0 = ((tid >> 4) + s * 32) * 4;
                const float* gp = tgt + (size_t)(b * 256 + k0) * NPIX_ + gn1 + pn4;
                #pragma unroll
                for (int i = 0; i < 4; i++)
                    pf[s * 4 + i] = *(const float4*)(gp + (size_t)i * NPIX_);
            }
        }

        // P1: q_h = relu(Wq1*x + b)
        f4v zz = {0.f, 0.f, 0.f, 0.f};
        f4v a1c[4] = {zz, zz, zz, zz};
        #pragma unroll
        for (int ks = 0; ks < 8; ks++) {
            const int kb = ks * 32 + kbq;
            const int cch = kb >> 3;
            bf8v a = *(const bf8v*)(Wq1 + (m0 + lr) * 256 + kb);
            bf8v bx[4];
            #pragma unroll
            for (int nt = 0; nt < 4; nt++) {
                const int row = nt * 16 + lr;
                bx[nt] = *(const bf8v*)(xT + row * 256 + ((cch ^ (row & 31)) << 3));
            }
            #pragma unroll
            for (int nt = 0; nt < 4; nt++)
                a1c[nt] = MFMA(a, bx[nt], a1c[nt]);
        }
        {
            const float4 b4 = *(const float4*)(bq1 + m0 + qd * 4);
            #pragma unroll
            for (int nt = 0; nt < 4; nt++) {
                ushort4 t;
                t.x = f2bf(fmaxf(a1c[nt][0] + b4.x, 0.f));
                t.y = f2bf(fmaxf(a1c[nt][1] + b4.y, 0.f));
                t.z = f2bf(fmaxf(a1c[nt][2] + b4.z, 0.f));
                t.w = f2bf(fmaxf(a1c[nt][3] + b4.w, 0.f));
                *(ushort4*)(hT + (nt * 16 + lr) * 136 + m0 + qd * 4) = t;
            }
        }
        __syncthreads();

        // P2: query = softplus(Wq2*q_h + b)
        f4v a2c[4] = {zz, zz, zz, zz};
        #pragma unroll
        for (int ks = 0; ks < 4; ks++) {
            const int kb = ks * 32 + kbq;
            bf8v a = *(const bf8v*)(Wq2 + (m0 + lr) * 128 + kb);
            bf8v bh[4];
            #pragma unroll
            for (int nt = 0; nt < 4; nt++)
                bh[nt] = *(const bf8v*)(hT + (nt * 16 + lr) * 136 + kb);
            #pragma unroll
            for (int nt = 0; nt < 4; nt++)
                a2c[nt] = MFMA(a, bh[nt], a2c[nt]);
        }
        __syncthreads();   // q_h reads done, overwrite hT with query
        {
            const float4 b4 = *(const float4*)(bq2 + m0 + qd * 4);
            const float* bp = (const float*)&b4;
            #pragma unroll
            for (int nt = 0; nt < 4; nt++) {
                ushort4 t;
                t.x = f2bf(softplus_f(a2c[nt][0] + bp[0]));
                t.y = f2bf(softplus_f(a2c[nt][1] + bp[1]));
                t.z = f2bf(softplus_f(a2c[nt][2] + bp[2]));
                t.w = f2bf(softplus_f(a2c[nt][3] + bp[3]));
                *(ushort4*)(hT + (nt * 16 + lr) * 136 + m0 + qd * 4) = t;
            }
        }
        __syncthreads();

        // fp32 denom (tid<64), then P3: out = S.q
        if (tid < 64) {
            const unsigned short* qr = hT + tid * 136;
            float s = 0.f;
            #pragma unroll
            for (int d = 0; d < 128; d += 8) {
                uint4 t = *(const uint4*)(qr + d);
                s = fmaf(Zsh[d + 0], lo16(t.x), s);
                s = fmaf(Zsh[d + 1], hi16(t.x), s);
                s = fmaf(Zsh[d + 2], lo16(t.y), s);
                s = fmaf(Zsh[d + 3], hi16(t.y), s);
                s = fmaf(Zsh[d + 4], lo16(t.z), s);
                s = fmaf(Zsh[d + 5], hi16(t.z), s);
                s = fmaf(Zsh[d + 6], lo16(t.w), s);
                s = fmaf(Zsh[d + 7], hi16(t.w), s);
            }
            dn[tid] = fmaxf(s, EPS_);
        }
        f4v oacc[4] = {zz, zz, zz, zz};
        #pragma unroll
        for (int ks = 0; ks < 4; ks++) {
            const int kb = ks * 32 + kbq;
            bf8v a = *(const bf8v*)(Sbf + (size_t)b * 16384 + (m0 + lr) * 128 + kb);
            bf8v bq[4];
            #pragma unroll
            for (int nt = 0; nt < 4; nt++)
                bq[nt] = *(const bf8v*)(hT + (nt * 16 + lr) * 136 + kb);
            #pragma unroll
            for (int nt = 0; nt < 4; nt++)
                oacc[nt] = MFMA(a, bq[nt], oacc[nt]);
        }
        __syncthreads();   // dn visible to all

        float inv[4];
        #pragma unroll
        for (int nt = 0; nt < 4; nt++) inv[nt] = 1.f / dn[nt * 16 + lr];
        #pragma unroll
        for (int nt = 0; nt < 4; nt++)
            #pragma unroll
            for (int r = 0; r < 4; r++) {
                const int m = m0 + qd * 4 + r;
                out[(size_t)(b * 128 + m) * NPIX_ + gn0 + nt * 16 + lr] = oacc[nt][r] * inv[nt];
            }
    }
}

extern "C" void kernel_launch(void* const* d_in, const int* in_sizes, int n_in,
                              void* d_out, int out_size, void* d_ws, size_t ws_size,
                              hipStream_t stream)
{
    const float* tgt = (const float*)d_in[0];
    const float* src = (const float*)d_in[1];
    char* ws = (char*)d_ws;
    unsigned short* Wk1 = (unsigned short*)(ws + OFF_WK1);
    unsigned short* Wv  = (unsigned short*)(ws + OFF_WV);
    unsigned short* Wq1 = (unsigned short*)(ws + OFF_WQ1);
    unsigned short* Wk2 = (unsigned short*)(ws + OFF_WK2);
    unsigned short* Wq2 = (unsigned short*)(ws + OFF_WQ2);
    float* bias = (float*)(ws + OFF_BIAS);
    float* Sbuf = (float*)(ws + OFF_S);
    float* Zbuf = (float*)(ws + OFF_Z);
    unsigned short* Sbf = (unsigned short*)(ws + OFF_SBF);
    unsigned short* valg = (unsigned short*)(ws + OFF_VAL);
    unsigned short* keyg = (unsigned short*)(ws + OFF_KEY);

    PrepPtrs p;
    p.w[0] = (const float*)d_in[4];  // k_w1
    p.w[1] = (const float*)d_in[6];  // v_w
    p.w[2] = (const float*)d_in[2];  // q_w1
    p.w[3] = (const float*)d_in[5];  // k_w2
    p.w[4] = (const float*)d_in[3];  // q_w2
    const int gbase[5] = {15, 23, 7, 19, 11}; // k1, v, q1, k2, q2 BN bases
    for (int c = 0; c < 5; c++) {
        p.g[c]  = (const float*)d_in[gbase[c]];
        p.be[c] = (const float*)d_in[gbase[c] + 1];
        p.mu[c] = (const float*)d_in[gbase[c] + 2];
        p.va[c] = (const float*)d_in[gbase[c] + 3];
    }
    p.wout[0] = Wk1; p.wout[1] = Wv; p.wout[2] = Wq1; p.wout[3] = Wk2; p.wout[4] = Wq2;
    p.bout[0] = bias; p.bout[1] = bias + 128; p.bout[2] = bias + 256;
    p.bout[3] = bias + 384; p.bout[4] = bias + 512;

    hipMemsetAsync(ws + OFF_S, 0, 524288 + 4096, stream);
    hipLaunchKernelGGL(prep_kernel, dim3(515), dim3(256), 0, stream, p);
    hipLaunchKernelGGL(srcKV, dim3(128, 8), dim3(512), 0, stream,
                       src, Wk1, Wv, Wk2, bias, valg, keyg);
    hipLaunchKernelGGL(skern, dim3(512), dim3(256), 0, stream, valg, keyg, Sbuf, Zbuf);
    hipLaunchKernelGGL(cvts, dim3(512), dim3(256), 0, stream, Sbuf, Sbf);
    hipLaunchKernelGGL(tgtAttn, dim3(128, 8), dim3(512), 0, stream,
                       tgt, Wq1, Wq2, bias, Sbf, Zbuf, (float*)d_out);
}

// Round 4
// 613.780 us; speedup vs baseline: 1.0366x; 1.0366x over previous
//
#include <hip/hip_runtime.h>
#include <math.h>

typedef __attribute__((ext_vector_type(8))) short bf8v;
typedef __attribute__((ext_vector_type(4))) float f4v;

#define B_      8
#define CIN_    256
#define C_      128
#define NPIX_   16384
#define EPS_    1e-12f
#define BN_EPS_ 1e-5f
#define TPB_    4

// workspace byte offsets (all 256-aligned)
#define OFF_WK1  0u          // 128x256 bf16
#define OFF_WV   65536u
#define OFF_WQ1  131072u
#define OFF_WK2  196608u     // 128x128 bf16
#define OFF_WQ2  229376u
#define OFF_BIAS 262144u     // 5*128 f32 [bk1,bv,bq1,bk2,bq2]
#define OFF_S    264704u     // 8*128*128 f32
#define OFF_Z    788992u     // 8*128 f32
#define OFF_SBF  793088u     // 8*128*128 bf16

__device__ __forceinline__ unsigned short f2bf(float f) {   // RNE
    unsigned u = __float_as_uint(f);
    unsigned r = u + 0x7fffu + ((u >> 16) & 1u);
    return (unsigned short)(r >> 16);
}
// truncation-pack two f32 -> bf16x2 in one v_perm_b32 (x staging only)
__device__ __forceinline__ unsigned packtr(float hi, float lo) {
    return __builtin_amdgcn_perm(__float_as_uint(hi), __float_as_uint(lo), 0x07060302u);
}
__device__ __forceinline__ float lo16(unsigned v){ return __uint_as_float(v << 16); }
__device__ __forceinline__ float hi16(unsigned v){ return __uint_as_float(v & 0xffff0000u); }
__device__ __forceinline__ float softplus_f(float x) {
    return fmaxf(x, 0.f) + __logf(1.f + __expf(-fabsf(x)));
}
__device__ __forceinline__ f4v MFMA(bf8v a, bf8v b, f4v c) {
    return __builtin_amdgcn_mfma_f32_16x16x32_bf16(a, b, c, 0, 0, 0);
}
// LDS swizzles: 16B-chunk XOR keeps b128 reads & ushort4 writes conflict-free
__device__ __forceinline__ int xcol(int row, int k)  { return (((k >> 3) ^ (row & 31)) << 3) | (k & 7); }
__device__ __forceinline__ int hcol(int row, int c)  { return (((c >> 3) ^ (row & 15)) << 3) | (c & 7); }

struct PrepPtrs {
    const float* w[5];
    const float* g[5];
    const float* be[5];
    const float* mu[5];
    const float* va[5];
    unsigned short* wout[5];
    float* bout[5];
};

// Fold BN into weights (bf16 RNE) + bias (f32). 0=k1,1=v,2=q1 (cin=256), 3=k2,4=q2 (cin=128)
__global__ void prep_kernel(PrepPtrs p) {
    int idx = blockIdx.x * 256 + threadIdx.x;
    if (idx < 131072) {
        int conv, local, sh;
        if (idx < 32768)       { conv = 0; local = idx;          sh = 8; }
        else if (idx < 65536)  { conv = 1; local = idx - 32768;  sh = 8; }
        else if (idx < 98304)  { conv = 2; local = idx - 65536;  sh = 8; }
        else if (idx < 114688) { conv = 3; local = idx - 98304;  sh = 7; }
        else                   { conv = 4; local = idx - 114688; sh = 7; }
        int o = local >> sh;
        float scale = p.g[conv][o] * rsqrtf(p.va[conv][o] + BN_EPS_);
        p.wout[conv][local] = f2bf(p.w[conv][local] * scale);
    } else if (idx < 131712) {
        int j = idx - 131072;
        int conv = j >> 7;
        int o = j & 127;
        float scale = p.g[conv][o] * rsqrtf(p.va[conv][o] + BN_EPS_);
        p.bout[conv][o] = p.be[conv][o] - p.mu[conv][o] * scale;
    }
}

// ---- fused source branch: h,val,key per 64-px tile; S += val.key^T, Z += rowsum(key)
//      val/key never touch HBM; S/Z committed once per block via f32 atomics.
__global__ __launch_bounds__(512, 2)   // 2 blocks/CU -> VGPR<=128 (4 was blocks-semantics -> 64 VGPR + spills, R3)
void srcS(const float* __restrict__ src,
          const unsigned short* __restrict__ Wk1, const unsigned short* __restrict__ Wv,
          const unsigned short* __restrict__ Wk2, const float* __restrict__ bias,
          float* __restrict__ Sbuf, float* __restrict__ Zbuf)
{
    __shared__ __align__(16) char smem[49152];
    unsigned short* xT   = (unsigned short*)smem;            // [64][256] sw, 32 KB
    unsigned short* hT   = (unsigned short*)(smem + 32768);  // [64][128] sw, 16 KB
    unsigned short* stgV = (unsigned short*)smem;            // [128][72] aliases xT (post-P2)
    unsigned short* stgK = (unsigned short*)(smem + 18432);  // [128][72] aliases xT tail + hT head

    const int tid = threadIdx.x;
    const int L = tid & 63, w = tid >> 6;
    const int lr = L & 15, qd = L >> 4;
    const int b = blockIdx.y;
    const int m0 = w * 16;
    const int kbq = qd * 8;
    const float* bk1 = bias;
    const float* bvp = bias + 128;
    const float* bk2 = bias + 384;
    const int pn4 = (tid & 15) * 4;
    const int zc = tid >> 2, zo = (tid & 3) * 16;   // Z: thread sums 16 px of channel zc

    f4v zz = {0.f, 0.f, 0.f, 0.f};
    f4v Sacc[8];
    #pragma unroll
    for (int i = 0; i < 8; i++) Sacc[i] = zz;
    float zacc = 0.f;

    float4 pf[8];
    int tile = blockIdx.x * TPB_;
    {   // prologue prefetch tile 0
        const int gn0 = tile * 64;
        #pragma unroll
        for (int s = 0; s < 2; s++) {
            const int k0 = ((tid >> 4) + s * 32) * 4;
            const float* gp = src + (size_t)(b * 256 + k0) * NPIX_ + gn0 + pn4;
            #pragma unroll
            for (int i = 0; i < 4; i++)
                pf[s * 4 + i] = *(const float4*)(gp + (size_t)i * NPIX_);
        }
    }

    for (int tt = 0; tt < TPB_; tt++, tile++) {
        if (tt) __syncthreads();   // prior S-phase stg reads done before overwrite
        // stage xT (truncation pack via v_perm)
        #pragma unroll
        for (int s = 0; s < 2; s++) {
            const int k0 = ((tid >> 4) + s * 32) * 4;
            #pragma unroll
            for (int j = 0; j < 4; j++) {
                const int row = pn4 + j;
                uint2 t;
                t.x = packtr(((const float*)&pf[s*4+1])[j], ((const float*)&pf[s*4+0])[j]);
                t.y = packtr(((const float*)&pf[s*4+3])[j], ((const float*)&pf[s*4+2])[j]);
                *(uint2*)(xT + row * 256 + xcol(row, k0)) = t;
            }
        }
        __syncthreads();

        // P1: h = Wk1*x, val = Wv*x  (per wave: 16 out-ch x 64 px)
        f4v hA[4] = {zz, zz, zz, zz}, vA[4] = {zz, zz, zz, zz};
        #pragma unroll
        for (int ks = 0; ks < 8; ks++) {
            const int kb = ks * 32 + kbq;
            bf8v a1 = *(const bf8v*)(Wk1 + (m0 + lr) * 256 + kb);
            bf8v a2 = *(const bf8v*)(Wv  + (m0 + lr) * 256 + kb);
            bf8v bx[4];
            #pragma unroll
            for (int nt = 0; nt < 4; nt++) {
                const int row = nt * 16 + lr;
                bx[nt] = *(const bf8v*)(xT + row * 256 + xcol(row, kb));
            }
            #pragma unroll
            for (int nt = 0; nt < 4; nt++) {
                hA[nt] = MFMA(a1, bx[nt], hA[nt]);
                vA[nt] = MFMA(a2, bx[nt], vA[nt]);
            }
        }
        // refill prefetch here (xT consumed; pf dead during P1 above -> keeps peak VGPR low)
        if (tt + 1 < TPB_) {
            const int gn1 = (tile + 1) * 64;
            #pragma unroll
            for (int s = 0; s < 2; s++) {
                const int k0 = ((tid >> 4) + s * 32) * 4;
                const float* gp = src + (size_t)(b * 256 + k0) * NPIX_ + gn1 + pn4;
                #pragma unroll
                for (int i = 0; i < 4; i++)
                    pf[s * 4 + i] = *(const float4*)(gp + (size_t)i * NPIX_);
            }
        }
        // h -> hT (bias+relu, RNE); val bias+relu in regs
        {
            const float4 b4 = *(const float4*)(bk1 + m0 + qd * 4);
            #pragma unroll
            for (int nt = 0; nt < 4; nt++) {
                const int row = nt * 16 + lr;
                ushort4 t;
                t.x = f2bf(fmaxf(hA[nt][0] + b4.x, 0.f));
                t.y = f2bf(fmaxf(hA[nt][1] + b4.y, 0.f));
                t.z = f2bf(fmaxf(hA[nt][2] + b4.z, 0.f));
                t.w = f2bf(fmaxf(hA[nt][3] + b4.w, 0.f));
                *(ushort4*)(hT + row * 128 + hcol(row, m0 + qd * 4)) = t;
            }
            const float4 bv4 = *(const float4*)(bvp + m0 + qd * 4);
            const float* bp = (const float*)&bv4;
            #pragma unroll
            for (int nt = 0; nt < 4; nt++)
                #pragma unroll
                for (int r = 0; r < 4; r++)
                    vA[nt][r] = fmaxf(vA[nt][r] + bp[r], 0.f);
        }
        __syncthreads();

        // P2: key = Wk2 * h
        f4v kA[4] = {zz, zz, zz, zz};
        #pragma unroll
        for (int ks = 0; ks < 4; ks++) {
            const int kb = ks * 32 + kbq;
            bf8v a = *(const bf8v*)(Wk2 + (m0 + lr) * 128 + kb);
            bf8v bh[4];
            #pragma unroll
            for (int nt = 0; nt < 4; nt++) {
                const int row = nt * 16 + lr;
                bh[nt] = *(const bf8v*)(hT + row * 128 + hcol(row, kb));
            }
            #pragma unroll
            for (int nt = 0; nt < 4; nt++)
                kA[nt] = MFMA(a, bh[nt], kA[nt]);
        }
        __syncthreads();   // hT reads done; stg regions (alias xT + hT head) free

        // stage val/key as [channel][pixel] for the S GEMM
        {
            const float4 bK4 = *(const float4*)(bk2 + m0 + qd * 4);
            const float* bp = (const float*)&bK4;
            #pragma unroll
            for (int nt = 0; nt < 4; nt++) {
                const int n = nt * 16 + lr;
                #pragma unroll
                for (int r = 0; r < 4; r++) {
                    const int m = m0 + qd * 4 + r;
                    stgV[m * 72 + n] = f2bf(vA[nt][r]);
                    stgK[m * 72 + n] = f2bf(softplus_f(kA[nt][r] + bp[r]));
                }
            }
        }
        __syncthreads();

        // S += val . key^T over this tile's 64 px (per wave: 16 val-ch x 128 key-ch)
        #pragma unroll
        for (int kk = 0; kk < 2; kk++) {
            const int kb = kk * 32 + kbq;
            bf8v a = *(const bf8v*)(stgV + (m0 + lr) * 72 + kb);
            bf8v bb[8];
            #pragma unroll
            for (int nt = 0; nt < 8; nt++)
                bb[nt] = *(const bf8v*)(stgK + (nt * 16 + lr) * 72 + kb);
            #pragma unroll
            for (int nt = 0; nt < 8; nt++)
                Sacc[nt] = MFMA(a, bb[nt], Sacc[nt]);
        }
        // Z partial: 16 px of channel zc
        {
            const unsigned short* kr = stgK + zc * 72 + zo;
            uint4 t0 = *(const uint4*)kr;
            uint4 t1 = *(const uint4*)(kr + 8);
            zacc += lo16(t0.x) + hi16(t0.x) + lo16(t0.y) + hi16(t0.y)
                  + lo16(t0.z) + hi16(t0.z) + lo16(t0.w) + hi16(t0.w)
                  + lo16(t1.x) + hi16(t1.x) + lo16(t1.y) + hi16(t1.y)
                  + lo16(t1.z) + hi16(t1.z) + lo16(t1.w) + hi16(t1.w);
        }
    }

    // commit partials
    #pragma unroll
    for (int nt = 0; nt < 8; nt++)
        #pragma unroll
        for (int r = 0; r < 4; r++) {
            const int m = m0 + qd * 4 + r;
            const int n = nt * 16 + lr;
            atomicAdd(Sbuf + ((size_t)b * 128 + m) * 128 + n, Sacc[nt][r]);
        }
    atomicAdd(Zbuf + b * 128 + zc, zacc);
}

__global__ void cvts(const float* __restrict__ Sbuf, unsigned short* __restrict__ Sbf) {
    int i = blockIdx.x * 256 + threadIdx.x;
    if (i < 131072) Sbf[i] = f2bf(Sbuf[i]);
}

// ---- target branch fused: q1 -> q2 -> S.q / max(Z.q,eps) ----
__global__ __launch_bounds__(512, 2)
void tgtAttn(const float* __restrict__ tgt,
             const unsigned short* __restrict__ Wq1, const unsigned short* __restrict__ Wq2,
             const float* __restrict__ bias, const unsigned short* __restrict__ Sbf,
             const float* __restrict__ Zbuf, float* __restrict__ out)
{
    __shared__ __align__(16) char smem[49920];
    unsigned short* xT = (unsigned short*)smem;            // [64][256] sw
    unsigned short* hT = (unsigned short*)(smem + 32768);  // [64][128] sw: q_h then query
    float* dn  = (float*)(smem + 49152);                   // [64]
    float* Zsh = (float*)(smem + 49408);                   // [128]

    const int tid = threadIdx.x;
    const int L = tid & 63, w = tid >> 6;
    const int lr = L & 15, qd = L >> 4;
    const int b = blockIdx.y;
    const int m0 = w * 16;
    const int kbq = qd * 8;
    const float* bq1 = bias + 256;
    const float* bq2 = bias + 512;
    const int pn4 = (tid & 15) * 4;

    if (tid < 128) Zsh[tid] = Zbuf[b * 128 + tid];

    f4v zz = {0.f, 0.f, 0.f, 0.f};
    float4 pf[8];
    int tile = blockIdx.x * TPB_;
    {
        const int gn0 = tile * 64;
        #pragma unroll
        for (int s = 0; s < 2; s++) {
            const int k0 = ((tid >> 4) + s * 32) * 4;
            const float* gp = tgt + (size_t)(b * 256 + k0) * NPIX_ + gn0 + pn4;
            #pragma unroll
            for (int i = 0; i < 4; i++)
                pf[s * 4 + i] = *(const float4*)(gp + (size_t)i * NPIX_);
        }
    }

    for (int tt = 0; tt < TPB_; tt++, tile++) {
        const int gn0 = tile * 64;
        #pragma unroll
        for (int s = 0; s < 2; s++) {
            const int k0 = ((tid >> 4) + s * 32) * 4;
            #pragma unroll
            for (int j = 0; j < 4; j++) {
                const int row = pn4 + j;
                uint2 t;
                t.x = packtr(((const float*)&pf[s*4+1])[j], ((const float*)&pf[s*4+0])[j]);
                t.y = packtr(((const float*)&pf[s*4+3])[j], ((const float*)&pf[s*4+2])[j]);
                *(uint2*)(xT + row * 256 + xcol(row, k0)) = t;
            }
        }
        __syncthreads();

        // P1: q_h = relu(Wq1*x + b)
        f4v a1c[4] = {zz, zz, zz, zz};
        #pragma unroll
        for (int ks = 0; ks < 8; ks++) {
            const int kb = ks * 32 + kbq;
            bf8v a = *(const bf8v*)(Wq1 + (m0 + lr) * 256 + kb);
            bf8v bx[4];
            #pragma unroll
            for (int nt = 0; nt < 4; nt++) {
                const int row = nt * 16 + lr;
                bx[nt] = *(const bf8v*)(xT + row * 256 + xcol(row, kb));
            }
            #pragma unroll
            for (int nt = 0; nt < 4; nt++)
                a1c[nt] = MFMA(a, bx[nt], a1c[nt]);
        }
        if (tt + 1 < TPB_) {   // refill prefetch (xT consumed)
            const int gn1 = (tile + 1) * 64;
            #pragma unroll
            for (int s = 0; s < 2; s++) {
                const int k0 = ((tid >> 4) + s * 32) * 4;
                const float* gp = tgt + (size_t)(b * 256 + k0) * NPIX_ + gn1 + pn4;
                #pragma unroll
                for (int i = 0; i < 4; i++)
                    pf[s * 4 + i] = *(const float4*)(gp + (size_t)i * NPIX_);
            }
        }
        {
            const float4 b4 = *(const float4*)(bq1 + m0 + qd * 4);
            #pragma unroll
            for (int nt = 0; nt < 4; nt++) {
                const int row = nt * 16 + lr;
                ushort4 t;
                t.x = f2bf(fmaxf(a1c[nt][0] + b4.x, 0.f));
                t.y = f2bf(fmaxf(a1c[nt][1] + b4.y, 0.f));
                t.z = f2bf(fmaxf(a1c[nt][2] + b4.z, 0.f));
                t.w = f2bf(fmaxf(a1c[nt][3] + b4.w, 0.f));
                *(ushort4*)(hT + row * 128 + hcol(row, m0 + qd * 4)) = t;
            }
        }
        __syncthreads();

        // P2: query = softplus(Wq2*q_h + b)
        f4v a2c[4] = {zz, zz, zz, zz};
        #pragma unroll
        for (int ks = 0; ks < 4; ks++) {
            const int kb = ks * 32 + kbq;
            bf8v a = *(const bf8v*)(Wq2 + (m0 + lr) * 128 + kb);
            bf8v bh[4];
            #pragma unroll
            for (int nt = 0; nt < 4; nt++) {
                const int row = nt * 16 + lr;
                bh[nt] = *(const bf8v*)(hT + row * 128 + hcol(row, kb));
            }
            #pragma unroll
            for (int nt = 0; nt < 4; nt++)
                a2c[nt] = MFMA(a, bh[nt], a2c[nt]);
        }
        __syncthreads();   // q_h reads done; overwrite hT with query
        {
            const float4 b4 = *(const float4*)(bq2 + m0 + qd * 4);
            const float* bp = (const float*)&b4;
            #pragma unroll
            for (int nt = 0; nt < 4; nt++) {
                const int row = nt * 16 + lr;
                ushort4 t;
                t.x = f2bf(softplus_f(a2c[nt][0] + bp[0]));
                t.y = f2bf(softplus_f(a2c[nt][1] + bp[1]));
                t.z = f2bf(softplus_f(a2c[nt][2] + bp[2]));
                t.w = f2bf(softplus_f(a2c[nt][3] + bp[3]));
                *(ushort4*)(hT + row * 128 + hcol(row, m0 + qd * 4)) = t;
            }
        }
        __syncthreads();

        // fp32 denom from LDS query (swizzle-aware chunk reads)
        if (tid < 64) {
            const int row = tid;
            const unsigned short* qr = hT + row * 128;
            float s = 0.f;
            #pragma unroll
            for (int ch = 0; ch < 16; ch++) {
                const int d = ch * 8;
                uint4 t = *(const uint4*)(qr + (((ch ^ (row & 15))) << 3));
                s = fmaf(Zsh[d + 0], lo16(t.x), s);
                s = fmaf(Zsh[d + 1], hi16(t.x), s);
                s = fmaf(Zsh[d + 2], lo16(t.y), s);
                s = fmaf(Zsh[d + 3], hi16(t.y), s);
                s = fmaf(Zsh[d + 4], lo16(t.z), s);
                s = fmaf(Zsh[d + 5], hi16(t.z), s);
                s = fmaf(Zsh[d + 6], lo16(t.w), s);
                s = fmaf(Zsh[d + 7], hi16(t.w), s);
            }
            dn[tid] = fmaxf(s, EPS_);
        }
        // P3: out = S.q
        f4v oacc[4] = {zz, zz, zz, zz};
        #pragma unroll
        for (int ks = 0; ks < 4; ks++) {
            const int kb = ks * 32 + kbq;
            bf8v a = *(const bf8v*)(Sbf + (size_t)b * 16384 + (m0 + lr) * 128 + kb);
            bf8v bq[4];
            #pragma unroll
            for (int nt = 0; nt < 4; nt++) {
                const int row = nt * 16 + lr;
                bq[nt] = *(const bf8v*)(hT + row * 128 + hcol(row, kb));
            }
            #pragma unroll
            for (int nt = 0; nt < 4; nt++)
                oacc[nt] = MFMA(a, bq[nt], oacc[nt]);
        }
        __syncthreads();   // dn visible; also gates next-tile xT overwrite

        float inv[4];
        #pragma unroll
        for (int nt = 0; nt < 4; nt++) inv[nt] = 1.f / dn[nt * 16 + lr];
        #pragma unroll
        for (int nt = 0; nt < 4; nt++)
            #pragma unroll
            for (int r = 0; r < 4; r++) {
                const int m = m0 + qd * 4 + r;
                out[(size_t)(b * 128 + m) * NPIX_ + gn0 + nt * 16 + lr] = oacc[nt][r] * inv[nt];
            }
    }
}

extern "C" void kernel_launch(void* const* d_in, const int* in_sizes, int n_in,
                              void* d_out, int out_size, void* d_ws, size_t ws_size,
                              hipStream_t stream)
{
    const float* tgt = (const float*)d_in[0];
    const float* src = (const float*)d_in[1];
    char* ws = (char*)d_ws;
    unsigned short* Wk1 = (unsigned short*)(ws + OFF_WK1);
    unsigned short* Wv  = (unsigned short*)(ws + OFF_WV);
    unsigned short* Wq1 = (unsigned short*)(ws + OFF_WQ1);
    unsigned short* Wk2 = (unsigned short*)(ws + OFF_WK2);
    unsigned short* Wq2 = (unsigned short*)(ws + OFF_WQ2);
    float* bias = (float*)(ws + OFF_BIAS);
    float* Sbuf = (float*)(ws + OFF_S);
    float* Zbuf = (float*)(ws + OFF_Z);
    unsigned short* Sbf = (unsigned short*)(ws + OFF_SBF);

    PrepPtrs p;
    p.w[0] = (const float*)d_in[4];  // k_w1
    p.w[1] = (const float*)d_in[6];  // v_w
    p.w[2] = (const float*)d_in[2];  // q_w1
    p.w[3] = (const float*)d_in[5];  // k_w2
    p.w[4] = (const float*)d_in[3];  // q_w2
    const int gbase[5] = {15, 23, 7, 19, 11}; // k1, v, q1, k2, q2 BN bases
    for (int c = 0; c < 5; c++) {
        p.g[c]  = (const float*)d_in[gbase[c]];
        p.be[c] = (const float*)d_in[gbase[c] + 1];
        p.mu[c] = (const float*)d_in[gbase[c] + 2];
        p.va[c] = (const float*)d_in[gbase[c] + 3];
    }
    p.wout[0] = Wk1; p.wout[1] = Wv; p.wout[2] = Wq1; p.wout[3] = Wk2; p.wout[4] = Wq2;
    p.bout[0] = bias; p.bout[1] = bias + 128; p.bout[2] = bias + 256;
    p.bout[3] = bias + 384; p.bout[4] = bias + 512;

    hipMemsetAsync(ws + OFF_S, 0, 524288 + 4096, stream);
    hipLaunchKernelGGL(prep_kernel, dim3(515), dim3(256), 0, stream, p);
    hipLaunchKernelGGL(srcS, dim3(NPIX_ / 64 / TPB_, B_), dim3(512), 0, stream,
                       src, Wk1, Wv, Wk2, bias, Sbuf, Zbuf);
    hipLaunchKernelGGL(cvts, dim3(512), dim3(256), 0, stream, Sbuf, Sbf);
    hipLaunchKernelGGL(tgtAttn, dim3(NPIX_ / 64 / TPB_, B_), dim3(512), 0, stream,
                       tgt, Wq1, Wq2, bias, Sbf, Zbuf, (float*)d_out);
}